// Round 1
// baseline (4196.943 us; speedup 1.0000x reference)
//
#include <hip/hip_runtime.h>
#include <hip/hip_bf16.h>

#define B_ 64
#define T_ 256
#define EMB_ 512
#define HID_ 1024
#define G4_ 4096
#define NCLS_ 32000

typedef _Float16 f16;
typedef _Float16 f16x8 __attribute__((ext_vector_type(8)));
typedef _Float16 f16x4 __attribute__((ext_vector_type(4)));
typedef float f32x4 __attribute__((ext_vector_type(4)));

__device__ __forceinline__ float sigm(float x) { return 1.f / (1.f + __expf(-x)); }

// ---------------- prep kernels ----------------

__global__ __launch_bounds__(256) void cvt_kernel(const float* __restrict__ src,
                                                  f16* __restrict__ dst, int n4) {
  int i = blockIdx.x * 256 + threadIdx.x;
  if (i < n4) {
    float4 v = ((const float4*)src)[i];
    f16x4 o = {(f16)v.x, (f16)v.y, (f16)v.z, (f16)v.w};
    *(f16x4*)(dst + (size_t)i * 4) = o;
  }
}

__global__ __launch_bounds__(256) void bsum_kernel(const float* __restrict__ a0,
                                                   const float* __restrict__ b0,
                                                   float* __restrict__ o0,
                                                   const float* __restrict__ a1,
                                                   const float* __restrict__ b1,
                                                   float* __restrict__ o1) {
  int i = blockIdx.x * 256 + threadIdx.x;
  if (i < G4_) {
    o0[i] = a0[i] + b0[i];
    o1[i] = a1[i] + b1[i];
  }
}

// x0 layout: [T][B][EMB] fp16
__global__ __launch_bounds__(128) void gather_kernel(const int* __restrict__ tokens,
                                                     const float* __restrict__ emb,
                                                     f16* __restrict__ x0) {
  int blk = blockIdx.x;  // t*64 + b
  int t = blk >> 6, b = blk & 63;
  int tok = tokens[b * T_ + t];
  float4 v = ((const float4*)(emb + (size_t)tok * EMB_))[threadIdx.x];
  f16x4 o = {(f16)v.x, (f16)v.y, (f16)v.z, (f16)v.w};
  *(f16x4*)(x0 + (size_t)blk * EMB_ + threadIdx.x * 4) = o;
}

// ---------------- pipelined step kernel ----------------
// stage 0: xg0[t=s]    = x0[t] @ W_ih0^T + bsum0          (blocks   0..63)
// stage 1: rec0 t=s-1  : h0,c0 update                      (blocks  64..127)
// stage 2: xg1[t=s-2]  = h0[t] @ W_ih1^T + bsum1          (blocks 128..191)
// stage 3: rec1 t=s-3  : h1,c1 update                      (blocks 192..255)
__global__ __launch_bounds__(256) void step_kernel(
    int s, const f16* __restrict__ x0, const f16* __restrict__ w0i,
    const f16* __restrict__ w0h, const f16* __restrict__ w1i,
    const f16* __restrict__ w1h, const float* __restrict__ b0s,
    const float* __restrict__ b1s, float* __restrict__ xg0,
    float* __restrict__ xg1, f16* __restrict__ h0r, f16* __restrict__ h1r,
    float* __restrict__ c0, float* __restrict__ c1) {
  const int stage = blockIdx.x >> 6;
  const int slice = blockIdx.x & 63;

  const f16* A;
  const f16* Bw;
  int K;
  bool isrec;
  if (stage == 0) {
    if (s > T_ - 1) return;
    A = x0 + (size_t)s * B_ * EMB_;
    Bw = w0i; K = EMB_; isrec = false;
  } else if (stage == 1) {
    if (s < 1 || s > T_) return;
    A = h0r + ((s - 2) & 1) * (B_ * HID_);  // h0[t-1]
    Bw = w0h; K = HID_; isrec = true;
  } else if (stage == 2) {
    if (s < 2 || s > T_ + 1) return;
    A = h0r + ((s - 2) & 1) * (B_ * HID_);  // h0[t]
    Bw = w1i; K = HID_; isrec = false;
  } else {
    if (s < 3 || s > T_ + 2) return;
    A = h1r + ((s - 4) & 1) * (B_ * HID_);  // h1[t-1]
    Bw = w1h; K = HID_; isrec = true;
  }

  __shared__ char smem[18432];
  f16* As = (f16*)smem;
  f16* Bs = (f16*)(smem + 9216);
  float* pre = (float*)smem;  // reused after K-loop (rec only)

  const int tid = threadIdx.x;
  const int lane = tid & 63, wave = tid >> 6;
  const int wm = wave & 1, wn = wave >> 1;
  const int lr = lane & 15, lk = lane >> 4;
  const int j0 = slice * 16;

  f32x4 acc[2][2] = {};

  const int nIter = K >> 6;
  for (int kt = 0; kt < nIter; ++kt) {
    const int k0 = kt << 6;
    __syncthreads();
#pragma unroll
    for (int i = 0; i < 2; ++i) {
      int id = tid + 256 * i;       // 0..511
      int r = id >> 3, c8 = id & 7; // row 0..63, 16B chunk 0..7
      uint4 av = *(const uint4*)(A + (size_t)r * K + k0 + c8 * 8);
      *(uint4*)(As + r * 72 + c8 * 8) = av;
      int brow = isrec ? ((r >> 4) * HID_ + j0 + (r & 15)) : (slice * 64 + r);
      uint4 bv = *(const uint4*)(Bw + (size_t)brow * K + k0 + c8 * 8);
      *(uint4*)(Bs + r * 72 + c8 * 8) = bv;
    }
    __syncthreads();
#pragma unroll
    for (int ks = 0; ks < 2; ++ks) {
      f16x8 a0 = *(const f16x8*)(As + (wm * 32 + lr) * 72 + ks * 32 + lk * 8);
      f16x8 a1 = *(const f16x8*)(As + (wm * 32 + 16 + lr) * 72 + ks * 32 + lk * 8);
      f16x8 b0 = *(const f16x8*)(Bs + (wn * 32 + lr) * 72 + ks * 32 + lk * 8);
      f16x8 b1 = *(const f16x8*)(Bs + (wn * 32 + 16 + lr) * 72 + ks * 32 + lk * 8);
      acc[0][0] = __builtin_amdgcn_mfma_f32_16x16x32_f16(a0, b0, acc[0][0], 0, 0, 0);
      acc[0][1] = __builtin_amdgcn_mfma_f32_16x16x32_f16(a0, b1, acc[0][1], 0, 0, 0);
      acc[1][0] = __builtin_amdgcn_mfma_f32_16x16x32_f16(a1, b0, acc[1][0], 0, 0, 0);
      acc[1][1] = __builtin_amdgcn_mfma_f32_16x16x32_f16(a1, b1, acc[1][1], 0, 0, 0);
    }
  }

  if (!isrec) {
    float* xgout = (stage == 0) ? xg0 + (s & 1) * (B_ * G4_)
                                : xg1 + (s & 1) * (B_ * G4_);
    const float* bs = (stage == 0) ? b0s : b1s;
#pragma unroll
    for (int mf = 0; mf < 2; ++mf)
#pragma unroll
      for (int nf = 0; nf < 2; ++nf) {
        int n = slice * 64 + wn * 32 + nf * 16 + lr;
        float bias = bs[n];
        int bbase = wm * 32 + mf * 16 + lk * 4;
#pragma unroll
        for (int rg = 0; rg < 4; ++rg)
          xgout[(bbase + rg) * G4_ + n] = acc[mf][nf][rg] + bias;
      }
    return;
  }

  // --- rec epilogue: exchange preacts via LDS, then LSTM elementwise ---
  __syncthreads();  // all waves done reading As/Bs
#pragma unroll
  for (int mf = 0; mf < 2; ++mf)
#pragma unroll
    for (int nf = 0; nf < 2; ++nf) {
      int nl = wn * 32 + nf * 16 + lr;       // 0..63 : gate-row within block
      int bl = wm * 32 + mf * 16 + lk * 4;   // batch base
      *(f32x4*)(pre + nl * 68 + bl) = acc[mf][nf];
    }
  __syncthreads();

  float* cbuf;
  f16* hout;
  const float* xg;
  if (stage == 1) {
    cbuf = c0;
    hout = h0r + ((s - 1) & 1) * (B_ * HID_);
    xg = xg0 + ((s - 1) & 1) * (B_ * G4_);
  } else {
    cbuf = c1;
    hout = h1r + ((s - 3) & 1) * (B_ * HID_);
    xg = xg1 + ((s - 3) & 1) * (B_ * G4_);
  }

#pragma unroll
  for (int i = 0; i < 4; ++i) {
    int id = tid + 256 * i;  // 0..1023
    int u = id & 15, b = id >> 4;
    int j = j0 + u;
    float pi = pre[u * 68 + b]        + xg[b * G4_ + j];
    float pf = pre[(16 + u) * 68 + b] + xg[b * G4_ + HID_ + j];
    float pg = pre[(32 + u) * 68 + b] + xg[b * G4_ + 2 * HID_ + j];
    float po = pre[(48 + u) * 68 + b] + xg[b * G4_ + 3 * HID_ + j];
    float ig = sigm(pi), fg = sigm(pf), gg = tanhf(pg), og = sigm(po);
    float cn = fg * cbuf[b * HID_ + j] + ig * gg;
    cbuf[b * HID_ + j] = cn;
    hout[b * HID_ + j] = (f16)(og * tanhf(cn));
  }
}

// ---------------- FC kernel: out = h1_last @ fc_w^T + fc_b ----------------
__global__ __launch_bounds__(256) void fc_kernel(const f16* __restrict__ A,
                                                 const float* __restrict__ fcw,
                                                 const float* __restrict__ fcb,
                                                 float* __restrict__ out) {
  const int n0 = blockIdx.x * 64;
  __shared__ char smem[18432];
  f16* As = (f16*)smem;
  f16* Bs = (f16*)(smem + 9216);
  const int tid = threadIdx.x;
  const int lane = tid & 63, wave = tid >> 6;
  const int wm = wave & 1, wn = wave >> 1;
  const int lr = lane & 15, lk = lane >> 4;
  f32x4 acc[2][2] = {};

  for (int kt = 0; kt < HID_ / 64; ++kt) {
    const int k0 = kt * 64;
    __syncthreads();
#pragma unroll
    for (int i = 0; i < 2; ++i) {
      int id = tid + 256 * i;
      int r = id >> 3, c8 = id & 7;
      uint4 av = *(const uint4*)(A + (size_t)r * HID_ + k0 + c8 * 8);
      *(uint4*)(As + r * 72 + c8 * 8) = av;
    }
#pragma unroll
    for (int i = 0; i < 4; ++i) {
      int id = tid + 256 * i;        // 0..1023
      int r = id >> 4, c4 = id & 15; // row, float4 chunk
      float4 v = *(const float4*)(fcw + (size_t)(n0 + r) * HID_ + k0 + c4 * 4);
      f16x4 o = {(f16)v.x, (f16)v.y, (f16)v.z, (f16)v.w};
      *(f16x4*)(Bs + r * 72 + c4 * 4) = o;
    }
    __syncthreads();
#pragma unroll
    for (int ks = 0; ks < 2; ++ks) {
      f16x8 a0 = *(const f16x8*)(As + (wm * 32 + lr) * 72 + ks * 32 + lk * 8);
      f16x8 a1 = *(const f16x8*)(As + (wm * 32 + 16 + lr) * 72 + ks * 32 + lk * 8);
      f16x8 b0 = *(const f16x8*)(Bs + (wn * 32 + lr) * 72 + ks * 32 + lk * 8);
      f16x8 b1 = *(const f16x8*)(Bs + (wn * 32 + 16 + lr) * 72 + ks * 32 + lk * 8);
      acc[0][0] = __builtin_amdgcn_mfma_f32_16x16x32_f16(a0, b0, acc[0][0], 0, 0, 0);
      acc[0][1] = __builtin_amdgcn_mfma_f32_16x16x32_f16(a0, b1, acc[0][1], 0, 0, 0);
      acc[1][0] = __builtin_amdgcn_mfma_f32_16x16x32_f16(a1, b0, acc[1][0], 0, 0, 0);
      acc[1][1] = __builtin_amdgcn_mfma_f32_16x16x32_f16(a1, b1, acc[1][1], 0, 0, 0);
    }
  }

#pragma unroll
  for (int mf = 0; mf < 2; ++mf)
#pragma unroll
    for (int nf = 0; nf < 2; ++nf) {
      int n = n0 + wn * 32 + nf * 16 + lr;
      float bias = fcb[n];
      int bbase = wm * 32 + mf * 16 + lk * 4;
#pragma unroll
      for (int rg = 0; rg < 4; ++rg)
        out[(size_t)(bbase + rg) * NCLS_ + n] = acc[mf][nf][rg] + bias;
    }
}

// ---------------- launch ----------------

extern "C" void kernel_launch(void* const* d_in, const int* in_sizes, int n_in,
                              void* d_out, int out_size, void* d_ws,
                              size_t ws_size, hipStream_t stream) {
  const int* tokens = (const int*)d_in[0];
  const float* emb = (const float*)d_in[1];
  const float* W_ih0 = (const float*)d_in[2];
  const float* W_hh0 = (const float*)d_in[3];
  const float* b_ih0 = (const float*)d_in[4];
  const float* b_hh0 = (const float*)d_in[5];
  const float* W_ih1 = (const float*)d_in[6];
  const float* W_hh1 = (const float*)d_in[7];
  const float* b_ih1 = (const float*)d_in[8];
  const float* b_hh1 = (const float*)d_in[9];
  const float* fc_w = (const float*)d_in[10];
  const float* fc_b = (const float*)d_in[11];
  float* out = (float*)d_out;

  char* ws = (char*)d_ws;
  size_t off = 0;
  auto carve = [&](size_t bytes) -> char* {
    char* p = ws + off;
    off += (bytes + 255) & ~(size_t)255;
    return p;
  };
  f16* w0i = (f16*)carve((size_t)G4_ * EMB_ * 2);
  f16* w0h = (f16*)carve((size_t)G4_ * HID_ * 2);
  f16* w1i = (f16*)carve((size_t)G4_ * HID_ * 2);
  f16* w1h = (f16*)carve((size_t)G4_ * HID_ * 2);
  f16* x0 = (f16*)carve((size_t)T_ * B_ * EMB_ * 2);
  float* b0s = (float*)carve(G4_ * 4);
  float* b1s = (float*)carve(G4_ * 4);
  float* xg0 = (float*)carve(2ull * B_ * G4_ * 4);
  float* xg1 = (float*)carve(2ull * B_ * G4_ * 4);
  char* state = carve(4ull * B_ * HID_ * 2 + 2ull * B_ * HID_ * 4);
  f16* h0r = (f16*)state;
  f16* h1r = (f16*)(state + 2 * B_ * HID_ * 2);
  float* c0 = (float*)(state + 4 * B_ * HID_ * 2);
  float* c1 = (float*)(state + 4 * B_ * HID_ * 2 + B_ * HID_ * 4);

  // zero h rings + c state (every call: deterministic)
  hipMemsetAsync(state, 0, 4ull * B_ * HID_ * 2 + 2ull * B_ * HID_ * 4, stream);

  cvt_kernel<<<(G4_ * EMB_ / 4 + 255) / 256, 256, 0, stream>>>(W_ih0, w0i, G4_ * EMB_ / 4);
  cvt_kernel<<<(G4_ * HID_ / 4 + 255) / 256, 256, 0, stream>>>(W_hh0, w0h, G4_ * HID_ / 4);
  cvt_kernel<<<(G4_ * HID_ / 4 + 255) / 256, 256, 0, stream>>>(W_ih1, w1i, G4_ * HID_ / 4);
  cvt_kernel<<<(G4_ * HID_ / 4 + 255) / 256, 256, 0, stream>>>(W_hh1, w1h, G4_ * HID_ / 4);
  bsum_kernel<<<(G4_ + 255) / 256, 256, 0, stream>>>(b_ih0, b_hh0, b0s, b_ih1, b_hh1, b1s);
  gather_kernel<<<T_ * B_, 128, 0, stream>>>(tokens, emb, x0);

  for (int s = 0; s <= T_ + 2; ++s)
    step_kernel<<<256, 256, 0, stream>>>(s, x0, w0i, w0h, w1i, w1h, b0s, b1s,
                                         xg0, xg1, h0r, h1r, c0, c1);

  fc_kernel<<<NCLS_ / 64, 256, 0, stream>>>(h1r + B_ * HID_, fc_w, fc_b, out);
}